// Round 1
// baseline (213.397 us; speedup 1.0000x reference)
//
#include <hip/hip_runtime.h>
#include <math.h>

#define E 8
#define DF 512
#define DE 128
#define H 8
#define S 64
#define GH 16
#define HD 16
#define B 2
#define NTOK 1024

__device__ __forceinline__ float wave_sum(float v) {
    for (int m = 32; m; m >>= 1) v += __shfl_xor(v, m, 64);
    return v;
}

// ---------------- kernel 1: deterministic expert token lists ----------------
__global__ void k_lists(const float* __restrict__ fp, unsigned* __restrict__ cnt,
                        unsigned* __restrict__ lst) {
    int e = blockIdx.x;
    int l = threadIdx.x;  // 64 threads = 1 wave
    unsigned c = 0;
    for (int base = 0; base < NTOK; base += 64) {
        int n = base + l;
        float f = fp[n];
        int ee = (int)(f * 8.0f);
        ee = ee > 7 ? 7 : ee;
        bool in = (ee == e);
        unsigned long long m = __ballot(in);
        unsigned pos = (unsigned)__popcll(m & ((1ull << l) - 1ull));
        if (in) lst[e * NTOK + c + pos] = (unsigned)n;
        c += (unsigned)__popcll(m);
    }
    if (l == 0) cnt[e] = c;
}

// ------------- kernel 2: LN + gate + QKV (own expert only), 1 wave/token -------------
__global__ __launch_bounds__(256) void k_lnqkv(
    const float* __restrict__ x, const float* __restrict__ fp,
    const float* __restrict__ lnw, const float* __restrict__ lnb,
    const float* __restrict__ alpha,
    const float* __restrict__ Wg1, const float* __restrict__ bg1,
    const float* __restrict__ Wg2, const float* __restrict__ bg2,
    const float* __restrict__ Wq, const float* __restrict__ Wk,
    const float* __restrict__ Wv,
    float* __restrict__ Q, float* __restrict__ K, float* __restrict__ V) {
    __shared__ float fsh[4][64];
    int wave = threadIdx.x >> 6;
    int lane = threadIdx.x & 63;
    int t = blockIdx.x * 4 + wave;       // t = b*NTOK + n
    int n = t & (NTOK - 1);

    const float* xrow = x + (size_t)t * DF;
    float4 a  = *(const float4*)(xrow + lane * 8);
    float4 b4 = *(const float4*)(xrow + lane * 8 + 4);
    float s  = a.x + a.y + a.z + a.w + b4.x + b4.y + b4.z + b4.w;
    float ss = a.x*a.x + a.y*a.y + a.z*a.z + a.w*a.w
             + b4.x*b4.x + b4.y*b4.y + b4.z*b4.z + b4.w*b4.w;
    s = wave_sum(s);
    ss = wave_sum(ss);
    float mu  = s * (1.0f / DF);
    float var = ss * (1.0f / DF) - mu * mu;
    float rs  = rsqrtf(var + 1e-5f);

    int e = (int)(fp[n] * 8.0f);
    e = e > 7 ? 7 : e;

    float xv = xrow[e * 64 + lane];
    float f = (xv - mu) * rs * lnw[e * 64 + lane] + lnb[e * 64 + lane];
    fsh[wave][lane] = f;
    __syncthreads();

    // gate MLP: 16 hidden, redundantly computed by each 16-lane group
    int h = lane & 15;
    const float* wg1 = Wg1 + (size_t)e * GH * S + (size_t)h * S;
    float g1 = bg1[e * GH + h];
#pragma unroll 8
    for (int si = 0; si < 64; si++) g1 += fsh[wave][si] * wg1[si];
    g1 = 0.5f * g1 * (1.0f + erff(g1 * 0.70710678118654752f));  // exact gelu
    float part = g1 * Wg2[e * GH + h];
    for (int m = 8; m; m >>= 1) part += __shfl_xor(part, m, 64);
    float g2 = part + bg2[e];
    float gate = 1.0f / (1.0f + expf(-g2));
    float aw = 1.0f / (1.0f + expf(-alpha[e]));
    float gm = gate * aw + (1.0f - aw);
    f *= gm;
    __syncthreads();
    fsh[wave][lane] = f;
    __syncthreads();

    // QKV: lane computes rows d=lane and d=lane+64 of each 128x64 matrix
    size_t wo = (size_t)e * DE * S;
    const float* Wqe = Wq + wo;
    const float* Wke = Wk + wo;
    const float* Wve = Wv + wo;
    float q0 = 0.f, q1 = 0.f, k0 = 0.f, k1 = 0.f, v0 = 0.f, v1 = 0.f;
#pragma unroll
    for (int s0 = 0; s0 < 64; s0 += 4) {
        float4 fv = *(const float4*)&fsh[wave][s0];
        float4 wq0 = *(const float4*)(Wqe + (size_t)lane * 64 + s0);
        float4 wq1 = *(const float4*)(Wqe + (size_t)(lane + 64) * 64 + s0);
        float4 wk0 = *(const float4*)(Wke + (size_t)lane * 64 + s0);
        float4 wk1 = *(const float4*)(Wke + (size_t)(lane + 64) * 64 + s0);
        float4 wv0 = *(const float4*)(Wve + (size_t)lane * 64 + s0);
        float4 wv1 = *(const float4*)(Wve + (size_t)(lane + 64) * 64 + s0);
        q0 += fv.x*wq0.x + fv.y*wq0.y + fv.z*wq0.z + fv.w*wq0.w;
        q1 += fv.x*wq1.x + fv.y*wq1.y + fv.z*wq1.z + fv.w*wq1.w;
        k0 += fv.x*wk0.x + fv.y*wk0.y + fv.z*wk0.z + fv.w*wk0.w;
        k1 += fv.x*wk1.x + fv.y*wk1.y + fv.z*wk1.z + fv.w*wk1.w;
        v0 += fv.x*wv0.x + fv.y*wv0.y + fv.z*wv0.z + fv.w*wv0.w;
        v1 += fv.x*wv1.x + fv.y*wv1.y + fv.z*wv1.z + fv.w*wv1.w;
    }
    size_t ob = (size_t)t * DE;
    Q[ob + lane] = q0; Q[ob + lane + 64] = q1;
    K[ob + lane] = k0; K[ob + lane + 64] = k1;
    V[ob + lane] = v0; V[ob + lane + 64] = v1;
}

// ---------------- kernel 3: block-diagonal attention, 1 thread/query ----------------
__global__ __launch_bounds__(256) void k_attn(
    const float* __restrict__ Q, const float* __restrict__ K,
    const float* __restrict__ V, const unsigned* __restrict__ cnt,
    const unsigned* __restrict__ lst, const float* __restrict__ temp,
    float* __restrict__ F) {
    int idx = blockIdx.x;          // b*64 + e*8 + h
    int b = idx >> 6;
    int e = (idx >> 3) & 7;
    int h = idx & 7;
    int c = (int)cnt[e];
    const unsigned* L = lst + e * NTOK;
    float inv_scale = 1.0f / (4.0f * fabsf(temp[0]));  // sqrt(HD)*|temp|

    for (int qi = threadIdx.x; qi < c; qi += 256) {
        int nq = (int)L[qi];
        const float* qp = Q + ((size_t)(b * NTOK + nq) * DE + h * HD);
        float4 q0 = *(const float4*)(qp + 0);
        float4 q1 = *(const float4*)(qp + 4);
        float4 q2 = *(const float4*)(qp + 8);
        float4 q3 = *(const float4*)(qp + 12);

        // pass 1: max
        float mx = -3.4e38f;
        for (int i = 0; i < c; i++) {
            int nk = (int)L[i];
            const float* kp = K + ((size_t)(b * NTOK + nk) * DE + h * HD);
            float4 k0 = *(const float4*)(kp + 0);
            float4 k1 = *(const float4*)(kp + 4);
            float4 k2 = *(const float4*)(kp + 8);
            float4 k3 = *(const float4*)(kp + 12);
            float d = q0.x*k0.x + q0.y*k0.y + q0.z*k0.z + q0.w*k0.w
                    + q1.x*k1.x + q1.y*k1.y + q1.z*k1.z + q1.w*k1.w
                    + q2.x*k2.x + q2.y*k2.y + q2.z*k2.z + q2.w*k2.w
                    + q3.x*k3.x + q3.y*k3.y + q3.z*k3.z + q3.w*k3.w;
            d *= inv_scale;
            mx = fmaxf(mx, d);
        }
        // pass 2: sum + PV
        float l = 0.f;
        float4 a0 = {0,0,0,0}, a1 = {0,0,0,0}, a2 = {0,0,0,0}, a3 = {0,0,0,0};
        for (int i = 0; i < c; i++) {
            int nk = (int)L[i];
            const float* kp = K + ((size_t)(b * NTOK + nk) * DE + h * HD);
            float4 k0 = *(const float4*)(kp + 0);
            float4 k1 = *(const float4*)(kp + 4);
            float4 k2 = *(const float4*)(kp + 8);
            float4 k3 = *(const float4*)(kp + 12);
            float d = q0.x*k0.x + q0.y*k0.y + q0.z*k0.z + q0.w*k0.w
                    + q1.x*k1.x + q1.y*k1.y + q1.z*k1.z + q1.w*k1.w
                    + q2.x*k2.x + q2.y*k2.y + q2.z*k2.z + q2.w*k2.w
                    + q3.x*k3.x + q3.y*k3.y + q3.z*k3.z + q3.w*k3.w;
            float p = expf(d * inv_scale - mx);
            l += p;
            const float* vp = V + ((size_t)(b * NTOK + nk) * DE + h * HD);
            float4 v0 = *(const float4*)(vp + 0);
            float4 v1 = *(const float4*)(vp + 4);
            float4 v2 = *(const float4*)(vp + 8);
            float4 v3 = *(const float4*)(vp + 12);
            a0.x += p*v0.x; a0.y += p*v0.y; a0.z += p*v0.z; a0.w += p*v0.w;
            a1.x += p*v1.x; a1.y += p*v1.y; a1.z += p*v1.z; a1.w += p*v1.w;
            a2.x += p*v2.x; a2.y += p*v2.y; a2.z += p*v2.z; a2.w += p*v2.w;
            a3.x += p*v3.x; a3.y += p*v3.y; a3.z += p*v3.z; a3.w += p*v3.w;
        }
        float il = 1.0f / l;
        float* op = F + ((size_t)(b * NTOK + nq) * DE + h * HD);
        ((float4*)op)[0] = make_float4(a0.x*il, a0.y*il, a0.z*il, a0.w*il);
        ((float4*)op)[1] = make_float4(a1.x*il, a1.y*il, a1.z*il, a1.w*il);
        ((float4*)op)[2] = make_float4(a2.x*il, a2.y*il, a2.z*il, a2.w*il);
        ((float4*)op)[3] = make_float4(a3.x*il, a3.y*il, a3.z*il, a3.w*il);
    }
}

// ---------------- kernel 4: proj (Wf^T) + bias + residual ----------------
__global__ __launch_bounds__(256) void k_proj(
    const float* __restrict__ x, const float* __restrict__ F,
    const float* __restrict__ Wf, const float* __restrict__ bf,
    float* __restrict__ out) {
    __shared__ float fr[DE];
    int t = blockIdx.x;
    int tid = threadIdx.x;
    if (tid < DE) fr[tid] = F[(size_t)t * DE + tid];
    __syncthreads();
#pragma unroll
    for (int d = tid; d < DF; d += 256) {
        const float* w = Wf + (size_t)d * DE;
        float acc = bf[d];
#pragma unroll
        for (int k0 = 0; k0 < DE; k0 += 4) {
            float4 wv = *(const float4*)(w + k0);
            acc += fr[k0]*wv.x + fr[k0+1]*wv.y + fr[k0+2]*wv.z + fr[k0+3]*wv.w;
        }
        out[(size_t)t * DF + d] = x[(size_t)t * DF + d] + acc;
    }
}

extern "C" void kernel_launch(void* const* d_in, const int* in_sizes, int n_in,
                              void* d_out, int out_size, void* d_ws, size_t ws_size,
                              hipStream_t stream) {
    (void)in_sizes; (void)n_in; (void)out_size; (void)ws_size;
    const float* x     = (const float*)d_in[0];
    const float* fp    = (const float*)d_in[1];
    const float* lnw   = (const float*)d_in[2];
    const float* lnb   = (const float*)d_in[3];
    const float* alpha = (const float*)d_in[4];
    const float* Wg1   = (const float*)d_in[5];
    const float* bg1   = (const float*)d_in[6];
    const float* Wg2   = (const float*)d_in[7];
    const float* bg2   = (const float*)d_in[8];
    const float* Wq    = (const float*)d_in[9];
    const float* Wk    = (const float*)d_in[10];
    const float* Wv    = (const float*)d_in[11];
    const float* temp  = (const float*)d_in[12];
    const float* Wf    = (const float*)d_in[13];
    const float* bf    = (const float*)d_in[14];
    float* out = (float*)d_out;

    char* ws = (char*)d_ws;
    unsigned* cnt = (unsigned*)ws;                 // 32 B
    unsigned* lst = (unsigned*)(ws + 1024);        // 32 KB
    float* Q = (float*)(ws + 65536);               // 1 MB each
    float* K = Q + (size_t)B * NTOK * DE;
    float* V = K + (size_t)B * NTOK * DE;
    float* F = V + (size_t)B * NTOK * DE;

    hipLaunchKernelGGL(k_lists, dim3(E), dim3(64), 0, stream, fp, cnt, lst);
    hipLaunchKernelGGL(k_lnqkv, dim3(B * NTOK / 4), dim3(256), 0, stream,
                       x, fp, lnw, lnb, alpha, Wg1, bg1, Wg2, bg2, Wq, Wk, Wv,
                       Q, K, V);
    hipLaunchKernelGGL(k_attn, dim3(B * E * H), dim3(256), 0, stream,
                       Q, K, V, cnt, lst, temp, F);
    hipLaunchKernelGGL(k_proj, dim3(B * NTOK), dim3(256), 0, stream,
                       x, F, Wf, bf, out);
}

// Round 2
// 127.266 us; speedup vs baseline: 1.6768x; 1.6768x over previous
//
#include <hip/hip_runtime.h>
#include <math.h>

#define E 8
#define DF 512
#define DE 128
#define H 8
#define S 64
#define GH 16
#define HD 16
#define B 2
#define NTOK 1024
#define QT 2          // query tiles per (b,e,h) group in k_attn
#define KMAX 256      // LDS-staged key capacity per group

__device__ __forceinline__ float wave_sum(float v) {
    for (int m = 32; m; m >>= 1) v += __shfl_xor(v, m, 64);
    return v;
}

// ---------------- kernel 1: deterministic expert token lists ----------------
__global__ void k_lists(const float* __restrict__ fp, unsigned* __restrict__ cnt,
                        unsigned* __restrict__ lst) {
    int e = blockIdx.x;
    int l = threadIdx.x;  // 64 threads = 1 wave
    unsigned c = 0;
    for (int base = 0; base < NTOK; base += 64) {
        int n = base + l;
        float f = fp[n];
        int ee = (int)(f * 8.0f);
        ee = ee > 7 ? 7 : ee;
        bool in = (ee == e);
        unsigned long long m = __ballot(in);
        unsigned pos = (unsigned)__popcll(m & ((1ull << l) - 1ull));
        if (in) lst[e * NTOK + c + pos] = (unsigned)n;
        c += (unsigned)__popcll(m);
    }
    if (l == 0) cnt[e] = c;
}

// ------------- kernel 2: LN + gate + QKV (own expert only), 1 wave/token -------------
__global__ __launch_bounds__(256) void k_lnqkv(
    const float* __restrict__ x, const float* __restrict__ fp,
    const float* __restrict__ lnw, const float* __restrict__ lnb,
    const float* __restrict__ alpha,
    const float* __restrict__ Wg1, const float* __restrict__ bg1,
    const float* __restrict__ Wg2, const float* __restrict__ bg2,
    const float* __restrict__ Wq, const float* __restrict__ Wk,
    const float* __restrict__ Wv,
    float* __restrict__ Q, float* __restrict__ K, float* __restrict__ V) {
    __shared__ float fsh[4][64];
    int wave = threadIdx.x >> 6;
    int lane = threadIdx.x & 63;
    int t = blockIdx.x * 4 + wave;       // t = b*NTOK + n
    int n = t & (NTOK - 1);

    const float* xrow = x + (size_t)t * DF;
    float4 a  = *(const float4*)(xrow + lane * 8);
    float4 b4 = *(const float4*)(xrow + lane * 8 + 4);
    float s  = a.x + a.y + a.z + a.w + b4.x + b4.y + b4.z + b4.w;
    float ss = a.x*a.x + a.y*a.y + a.z*a.z + a.w*a.w
             + b4.x*b4.x + b4.y*b4.y + b4.z*b4.z + b4.w*b4.w;
    s = wave_sum(s);
    ss = wave_sum(ss);
    float mu  = s * (1.0f / DF);
    float var = ss * (1.0f / DF) - mu * mu;
    float rs  = rsqrtf(var + 1e-5f);

    int e = (int)(fp[n] * 8.0f);
    e = e > 7 ? 7 : e;

    float xv = xrow[e * 64 + lane];
    float f = (xv - mu) * rs * lnw[e * 64 + lane] + lnb[e * 64 + lane];
    fsh[wave][lane] = f;
    __syncthreads();

    // gate MLP: 16 hidden, redundantly computed by each 16-lane group
    int h = lane & 15;
    const float* wg1 = Wg1 + (size_t)e * GH * S + (size_t)h * S;
    float g1 = bg1[e * GH + h];
#pragma unroll 8
    for (int si = 0; si < 64; si++) g1 += fsh[wave][si] * wg1[si];
    g1 = 0.5f * g1 * (1.0f + erff(g1 * 0.70710678118654752f));  // exact gelu
    float part = g1 * Wg2[e * GH + h];
    for (int m = 8; m; m >>= 1) part += __shfl_xor(part, m, 64);
    float g2 = part + bg2[e];
    float gate = 1.0f / (1.0f + __expf(-g2));
    float aw = 1.0f / (1.0f + __expf(-alpha[e]));
    float gm = gate * aw + (1.0f - aw);
    f *= gm;
    __syncthreads();
    fsh[wave][lane] = f;
    __syncthreads();

    // QKV: lane computes rows d=lane and d=lane+64 of each 128x64 matrix
    size_t wo = (size_t)e * DE * S;
    const float* Wqe = Wq + wo;
    const float* Wke = Wk + wo;
    const float* Wve = Wv + wo;
    float q0 = 0.f, q1 = 0.f, k0 = 0.f, k1 = 0.f, v0 = 0.f, v1 = 0.f;
#pragma unroll
    for (int s0 = 0; s0 < 64; s0 += 4) {
        float4 fv = *(const float4*)&fsh[wave][s0];
        float4 wq0 = *(const float4*)(Wqe + (size_t)lane * 64 + s0);
        float4 wq1 = *(const float4*)(Wqe + (size_t)(lane + 64) * 64 + s0);
        float4 wk0 = *(const float4*)(Wke + (size_t)lane * 64 + s0);
        float4 wk1 = *(const float4*)(Wke + (size_t)(lane + 64) * 64 + s0);
        float4 wv0 = *(const float4*)(Wve + (size_t)lane * 64 + s0);
        float4 wv1 = *(const float4*)(Wve + (size_t)(lane + 64) * 64 + s0);
        q0 += fv.x*wq0.x + fv.y*wq0.y + fv.z*wq0.z + fv.w*wq0.w;
        q1 += fv.x*wq1.x + fv.y*wq1.y + fv.z*wq1.z + fv.w*wq1.w;
        k0 += fv.x*wk0.x + fv.y*wk0.y + fv.z*wk0.z + fv.w*wk0.w;
        k1 += fv.x*wk1.x + fv.y*wk1.y + fv.z*wk1.z + fv.w*wk1.w;
        v0 += fv.x*wv0.x + fv.y*wv0.y + fv.z*wv0.z + fv.w*wv0.w;
        v1 += fv.x*wv1.x + fv.y*wv1.y + fv.z*wv1.z + fv.w*wv1.w;
    }
    size_t ob = (size_t)t * DE;
    Q[ob + lane] = q0; Q[ob + lane + 64] = q1;
    K[ob + lane] = k0; K[ob + lane + 64] = k1;
    V[ob + lane] = v0; V[ob + lane + 64] = v1;
}

// ---------------- kernel 3: block-diagonal attention, LDS-staged K/V ----------------
__global__ __launch_bounds__(256) void k_attn(
    const float* __restrict__ Q, const float* __restrict__ K,
    const float* __restrict__ V, const unsigned* __restrict__ cnt,
    const unsigned* __restrict__ lst, const float* __restrict__ temp,
    float* __restrict__ F) {
    __shared__ float Ksh[KMAX][HD];   // 16 KB
    __shared__ float Vsh[KMAX][HD];   // 16 KB
    int idx = blockIdx.x;             // ((b*E + e)*H + h)*QT + tile
    int tile = idx & (QT - 1);
    int beh = idx / QT;
    int b = beh >> 6;
    int e = (beh >> 3) & 7;
    int h = beh & 7;
    int c = (int)cnt[e];
    int cs = c < KMAX ? c : KMAX;
    const unsigned* L = lst + e * NTOK;
    float inv_scale = 1.0f / (4.0f * fabsf(temp[0]));  // 1/(sqrt(HD)*|temp|)

    // stage K,V rows for this group into LDS (float4 granularity)
    for (int j = threadIdx.x; j < cs * 4; j += 256) {
        int i = j >> 2, comp = j & 3;
        int nk = (int)L[i];
        size_t rb = (size_t)(b * NTOK + nk) * DE + h * HD;
        ((float4*)Ksh[i])[comp] = ((const float4*)(K + rb))[comp];
        ((float4*)Vsh[i])[comp] = ((const float4*)(V + rb))[comp];
    }
    __syncthreads();

    for (int qi = tile + QT * threadIdx.x; qi < c; qi += QT * 256) {
        int nq = (int)L[qi];
        const float* qp = Q + ((size_t)(b * NTOK + nq) * DE + h * HD);
        float4 q0 = ((const float4*)qp)[0];
        float4 q1 = ((const float4*)qp)[1];
        float4 q2 = ((const float4*)qp)[2];
        float4 q3 = ((const float4*)qp)[3];

        // pass 1: max (LDS broadcast reads)
        float mx = -3.4e38f;
        for (int i = 0; i < cs; i++) {
            float4 k0 = ((const float4*)Ksh[i])[0];
            float4 k1 = ((const float4*)Ksh[i])[1];
            float4 k2 = ((const float4*)Ksh[i])[2];
            float4 k3 = ((const float4*)Ksh[i])[3];
            float d = q0.x*k0.x + q0.y*k0.y + q0.z*k0.z + q0.w*k0.w
                    + q1.x*k1.x + q1.y*k1.y + q1.z*k1.z + q1.w*k1.w
                    + q2.x*k2.x + q2.y*k2.y + q2.z*k2.z + q2.w*k2.w
                    + q3.x*k3.x + q3.y*k3.y + q3.z*k3.z + q3.w*k3.w;
            mx = fmaxf(mx, d * inv_scale);
        }
        for (int i = cs; i < c; i++) {   // safety tail (never taken at this data)
            int nk = (int)L[i];
            const float* kp = K + ((size_t)(b * NTOK + nk) * DE + h * HD);
            float d = 0.f;
            for (int dd = 0; dd < HD; dd++) d += qp[dd] * kp[dd];
            mx = fmaxf(mx, d * inv_scale);
        }

        // pass 2: sum + PV
        float l = 0.f;
        float4 a0 = {0,0,0,0}, a1 = {0,0,0,0}, a2 = {0,0,0,0}, a3 = {0,0,0,0};
        for (int i = 0; i < cs; i++) {
            float4 k0 = ((const float4*)Ksh[i])[0];
            float4 k1 = ((const float4*)Ksh[i])[1];
            float4 k2 = ((const float4*)Ksh[i])[2];
            float4 k3 = ((const float4*)Ksh[i])[3];
            float d = q0.x*k0.x + q0.y*k0.y + q0.z*k0.z + q0.w*k0.w
                    + q1.x*k1.x + q1.y*k1.y + q1.z*k1.z + q1.w*k1.w
                    + q2.x*k2.x + q2.y*k2.y + q2.z*k2.z + q2.w*k2.w
                    + q3.x*k3.x + q3.y*k3.y + q3.z*k3.z + q3.w*k3.w;
            float p = __expf(d * inv_scale - mx);
            l += p;
            float4 v0 = ((const float4*)Vsh[i])[0];
            float4 v1 = ((const float4*)Vsh[i])[1];
            float4 v2 = ((const float4*)Vsh[i])[2];
            float4 v3 = ((const float4*)Vsh[i])[3];
            a0.x += p*v0.x; a0.y += p*v0.y; a0.z += p*v0.z; a0.w += p*v0.w;
            a1.x += p*v1.x; a1.y += p*v1.y; a1.z += p*v1.z; a1.w += p*v1.w;
            a2.x += p*v2.x; a2.y += p*v2.y; a2.z += p*v2.z; a2.w += p*v2.w;
            a3.x += p*v3.x; a3.y += p*v3.y; a3.z += p*v3.z; a3.w += p*v3.w;
        }
        for (int i = cs; i < c; i++) {   // safety tail
            int nk = (int)L[i];
            size_t rb = (size_t)(b * NTOK + nk) * DE + h * HD;
            const float* kp = K + rb;
            float d = 0.f;
            for (int dd = 0; dd < HD; dd++) d += qp[dd] * kp[dd];
            float p = __expf(d * inv_scale - mx);
            l += p;
            const float* vp = V + rb;
            a0.x += p*vp[0];  a0.y += p*vp[1];  a0.z += p*vp[2];  a0.w += p*vp[3];
            a1.x += p*vp[4];  a1.y += p*vp[5];  a1.z += p*vp[6];  a1.w += p*vp[7];
            a2.x += p*vp[8];  a2.y += p*vp[9];  a2.z += p*vp[10]; a2.w += p*vp[11];
            a3.x += p*vp[12]; a3.y += p*vp[13]; a3.z += p*vp[14]; a3.w += p*vp[15];
        }
        float il = 1.0f / l;
        float* op = F + ((size_t)(b * NTOK + nq) * DE + h * HD);
        ((float4*)op)[0] = make_float4(a0.x*il, a0.y*il, a0.z*il, a0.w*il);
        ((float4*)op)[1] = make_float4(a1.x*il, a1.y*il, a1.z*il, a1.w*il);
        ((float4*)op)[2] = make_float4(a2.x*il, a2.y*il, a2.z*il, a2.w*il);
        ((float4*)op)[3] = make_float4(a3.x*il, a3.y*il, a3.z*il, a3.w*il);
    }
}

// ---------------- kernel 4: proj (Wf^T) + bias + residual, 4 tokens/block ----------------
__global__ __launch_bounds__(256) void k_proj(
    const float* __restrict__ x, const float* __restrict__ F,
    const float* __restrict__ Wf, const float* __restrict__ bf,
    float* __restrict__ out) {
    __shared__ float fr[4][DE];       // 2 KB
    int t0 = blockIdx.x * 4;
    int tid = threadIdx.x;
    if (tid < 128) ((float4*)fr)[tid] = ((const float4*)(F + (size_t)t0 * DE))[tid];
    __syncthreads();
#pragma unroll
    for (int rep = 0; rep < 2; rep++) {
        int d = tid + rep * 256;
        const float* w = Wf + (size_t)d * DE;
        float acc0 = bf[d], acc1 = acc0, acc2 = acc0, acc3 = acc0;
#pragma unroll
        for (int k0 = 0; k0 < DE; k0 += 4) {
            float4 wv = *(const float4*)(w + k0);
            acc0 += fr[0][k0]*wv.x + fr[0][k0+1]*wv.y + fr[0][k0+2]*wv.z + fr[0][k0+3]*wv.w;
            acc1 += fr[1][k0]*wv.x + fr[1][k0+1]*wv.y + fr[1][k0+2]*wv.z + fr[1][k0+3]*wv.w;
            acc2 += fr[2][k0]*wv.x + fr[2][k0+1]*wv.y + fr[2][k0+2]*wv.z + fr[2][k0+3]*wv.w;
            acc3 += fr[3][k0]*wv.x + fr[3][k0+1]*wv.y + fr[3][k0+2]*wv.z + fr[3][k0+3]*wv.w;
        }
        out[(size_t)(t0 + 0) * DF + d] = x[(size_t)(t0 + 0) * DF + d] + acc0;
        out[(size_t)(t0 + 1) * DF + d] = x[(size_t)(t0 + 1) * DF + d] + acc1;
        out[(size_t)(t0 + 2) * DF + d] = x[(size_t)(t0 + 2) * DF + d] + acc2;
        out[(size_t)(t0 + 3) * DF + d] = x[(size_t)(t0 + 3) * DF + d] + acc3;
    }
}

extern "C" void kernel_launch(void* const* d_in, const int* in_sizes, int n_in,
                              void* d_out, int out_size, void* d_ws, size_t ws_size,
                              hipStream_t stream) {
    (void)in_sizes; (void)n_in; (void)out_size; (void)ws_size;
    const float* x     = (const float*)d_in[0];
    const float* fp    = (const float*)d_in[1];
    const float* lnw   = (const float*)d_in[2];
    const float* lnb   = (const float*)d_in[3];
    const float* alpha = (const float*)d_in[4];
    const float* Wg1   = (const float*)d_in[5];
    const float* bg1   = (const float*)d_in[6];
    const float* Wg2   = (const float*)d_in[7];
    const float* bg2   = (const float*)d_in[8];
    const float* Wq    = (const float*)d_in[9];
    const float* Wk    = (const float*)d_in[10];
    const float* Wv    = (const float*)d_in[11];
    const float* temp  = (const float*)d_in[12];
    const float* Wf    = (const float*)d_in[13];
    const float* bf    = (const float*)d_in[14];
    float* out = (float*)d_out;

    char* ws = (char*)d_ws;
    unsigned* cnt = (unsigned*)ws;                 // 32 B
    unsigned* lst = (unsigned*)(ws + 1024);        // 32 KB
    float* Q = (float*)(ws + 65536);               // 1 MB each
    float* K = Q + (size_t)B * NTOK * DE;
    float* V = K + (size_t)B * NTOK * DE;
    float* F = V + (size_t)B * NTOK * DE;

    hipLaunchKernelGGL(k_lists, dim3(E), dim3(64), 0, stream, fp, cnt, lst);
    hipLaunchKernelGGL(k_lnqkv, dim3(B * NTOK / 4), dim3(256), 0, stream,
                       x, fp, lnw, lnb, alpha, Wg1, bg1, Wg2, bg2, Wq, Wk, Wv,
                       Q, K, V);
    hipLaunchKernelGGL(k_attn, dim3(B * E * H * QT), dim3(256), 0, stream,
                       Q, K, V, cnt, lst, temp, F);
    hipLaunchKernelGGL(k_proj, dim3(B * NTOK / 4), dim3(256), 0, stream,
                       x, F, Wf, bf, out);
}

// Round 3
// 80.453 us; speedup vs baseline: 2.6524x; 1.5819x over previous
//
#include <hip/hip_runtime.h>
#include <math.h>

#define E 8
#define DF 512
#define DE 128
#define H 8
#define S 64
#define GH 16
#define HD 16
#define B 2
#define NTOK 1024
#define QT 2          // query tiles per (b,e,h) group in k_attn
#define KMAX 256      // LDS-staged key capacity per group

__device__ __forceinline__ float wave_sum(float v) {
    for (int m = 32; m; m >>= 1) v += __shfl_xor(v, m, 64);
    return v;
}

// ---------------- kernel 0: weight transposes (reduction dim -> row dim) ----------------
// WqT/WkT/WvT: [E][S][DE], Wg1T: [E][S][GH], WfT: [DE][DF]
__global__ __launch_bounds__(256) void k_transpose(
    const float* __restrict__ Wq, const float* __restrict__ Wk,
    const float* __restrict__ Wv, const float* __restrict__ Wg1,
    const float* __restrict__ Wf,
    float* __restrict__ WqT, float* __restrict__ WkT, float* __restrict__ WvT,
    float* __restrict__ Wg1T, float* __restrict__ WfT) {
    __shared__ float sh[64][65];
    int bid = blockIdx.x;
    int tid = threadIdx.x;
    const float* in;
    float* out;
    int rows, istride, ostride;
    if (bid < 48) {                 // Wq/Wk/Wv: [128][64] per expert -> [64][128]
        int m = bid >> 4, e = (bid >> 1) & 7, dt = bid & 1;
        const float* W = (m == 0) ? Wq : (m == 1) ? Wk : Wv;
        float* WT      = (m == 0) ? WqT : (m == 1) ? WkT : WvT;
        in = W + (size_t)e * DE * S + (size_t)dt * 64 * S;
        out = WT + (size_t)e * S * DE + dt * 64;
        rows = 64; istride = S; ostride = DE;
    } else if (bid < 64) {          // Wf: [512][128] -> [128][512]
        int i = bid - 48, rt = i >> 1, ct = i & 1;
        in = Wf + (size_t)rt * 64 * DE + ct * 64;
        out = WfT + (size_t)ct * 64 * DF + rt * 64;
        rows = 64; istride = DE; ostride = DF;
    } else {                        // Wg1: [16][64] per expert -> [64][16]
        int e = bid - 64;
        in = Wg1 + (size_t)e * GH * S;
        out = Wg1T + (size_t)e * S * GH;
        rows = GH; istride = S; ostride = GH;
    }
    int c = tid & 63, r0 = tid >> 6;
    for (int r = r0; r < rows; r += 4) sh[r][c] = in[(size_t)r * istride + c];
    __syncthreads();
    if (c < rows) {
        for (int cc = r0; cc < 64; cc += 4)
            out[(size_t)cc * ostride + c] = sh[c][cc];
    }
}

// ---------------- kernel 1: deterministic expert token lists ----------------
__global__ void k_lists(const float* __restrict__ fp, unsigned* __restrict__ cnt,
                        unsigned* __restrict__ lst) {
    int e = blockIdx.x;
    int l = threadIdx.x;  // 64 threads = 1 wave
    unsigned c = 0;
    for (int base = 0; base < NTOK; base += 64) {
        int n = base + l;
        float f = fp[n];
        int ee = (int)(f * 8.0f);
        ee = ee > 7 ? 7 : ee;
        bool in = (ee == e);
        unsigned long long m = __ballot(in);
        unsigned pos = (unsigned)__popcll(m & ((1ull << l) - 1ull));
        if (in) lst[e * NTOK + c + pos] = (unsigned)n;
        c += (unsigned)__popcll(m);
    }
    if (l == 0) cnt[e] = c;
}

// ------------- kernel 2: LN + gate + QKV (own expert only), 1 wave/token -------------
__global__ __launch_bounds__(256) void k_lnqkv(
    const float* __restrict__ x, const float* __restrict__ fp,
    const float* __restrict__ lnw, const float* __restrict__ lnb,
    const float* __restrict__ alpha,
    const float* __restrict__ Wg1T, const float* __restrict__ bg1,
    const float* __restrict__ Wg2, const float* __restrict__ bg2,
    const float* __restrict__ WqT, const float* __restrict__ WkT,
    const float* __restrict__ WvT,
    float* __restrict__ Q, float* __restrict__ K, float* __restrict__ V) {
    __shared__ float fsh[4][64];
    int wave = threadIdx.x >> 6;
    int lane = threadIdx.x & 63;
    int t = blockIdx.x * 4 + wave;       // t = b*NTOK + n
    int n = t & (NTOK - 1);

    const float* xrow = x + (size_t)t * DF;
    float4 a  = *(const float4*)(xrow + lane * 8);
    float4 b4 = *(const float4*)(xrow + lane * 8 + 4);
    float s  = a.x + a.y + a.z + a.w + b4.x + b4.y + b4.z + b4.w;
    float ss = a.x*a.x + a.y*a.y + a.z*a.z + a.w*a.w
             + b4.x*b4.x + b4.y*b4.y + b4.z*b4.z + b4.w*b4.w;
    s = wave_sum(s);
    ss = wave_sum(ss);
    float mu  = s * (1.0f / DF);
    float var = ss * (1.0f / DF) - mu * mu;
    float rs  = rsqrtf(var + 1e-5f);

    int e = (int)(fp[n] * 8.0f);
    e = e > 7 ? 7 : e;

    float xv = xrow[e * 64 + lane];
    float f = (xv - mu) * rs * lnw[e * 64 + lane] + lnb[e * 64 + lane];
    fsh[wave][lane] = f;
    __syncthreads();

    // gate MLP: h = lane&15, s-range split across the 4 sixteen-lane groups
    int h = lane & 15;
    int sb = (lane >> 4) * 16;
    const float* wg1t = Wg1T + (size_t)e * S * GH;
    float g1p = 0.f;
#pragma unroll
    for (int si = 0; si < 16; si++)
        g1p += fsh[wave][sb + si] * wg1t[(size_t)(sb + si) * GH + h];
    g1p += __shfl_xor(g1p, 16, 64);
    g1p += __shfl_xor(g1p, 32, 64);
    float g1 = g1p + bg1[e * GH + h];
    g1 = 0.5f * g1 * (1.0f + erff(g1 * 0.70710678118654752f));  // exact gelu
    float part = g1 * Wg2[e * GH + h];
    part += __shfl_xor(part, 1, 64);
    part += __shfl_xor(part, 2, 64);
    part += __shfl_xor(part, 4, 64);
    part += __shfl_xor(part, 8, 64);
    float g2 = part + bg2[e];
    float gate = 1.0f / (1.0f + __expf(-g2));
    float aw = 1.0f / (1.0f + __expf(-alpha[e]));
    float gm = gate * aw + (1.0f - aw);
    f *= gm;
    __syncthreads();
    fsh[wave][lane] = f;
    __syncthreads();

    // QKV: lane owns dims d = lane*2, lane*2+1; coalesced float2 weight rows
    size_t wo = (size_t)e * S * DE;
    const float* Wqe = WqT + wo;
    const float* Wke = WkT + wo;
    const float* Wve = WvT + wo;
    float2 qa = {0.f, 0.f}, ka = {0.f, 0.f}, va = {0.f, 0.f};
    int d2 = lane * 2;
#pragma unroll 4
    for (int si = 0; si < S; si++) {
        float fv = fsh[wave][si];
        float2 wq = *(const float2*)(Wqe + (size_t)si * DE + d2);
        float2 wk = *(const float2*)(Wke + (size_t)si * DE + d2);
        float2 wv = *(const float2*)(Wve + (size_t)si * DE + d2);
        qa.x += fv * wq.x; qa.y += fv * wq.y;
        ka.x += fv * wk.x; ka.y += fv * wk.y;
        va.x += fv * wv.x; va.y += fv * wv.y;
    }
    size_t ob = (size_t)t * DE + d2;
    *(float2*)(Q + ob) = qa;
    *(float2*)(K + ob) = ka;
    *(float2*)(V + ob) = va;
}

// ---------------- kernel 3: block-diagonal attention, LDS-staged K/V ----------------
__global__ __launch_bounds__(256) void k_attn(
    const float* __restrict__ Q, const float* __restrict__ K,
    const float* __restrict__ V, const unsigned* __restrict__ cnt,
    const unsigned* __restrict__ lst, const float* __restrict__ temp,
    float* __restrict__ F) {
    __shared__ float Ksh[KMAX][HD];   // 16 KB
    __shared__ float Vsh[KMAX][HD];   // 16 KB
    int idx = blockIdx.x;             // ((b*E + e)*H + h)*QT + tile
    int tile = idx & (QT - 1);
    int beh = idx / QT;
    int b = beh >> 6;
    int e = (beh >> 3) & 7;
    int h = beh & 7;
    int c = (int)cnt[e];
    int cs = c < KMAX ? c : KMAX;
    const unsigned* L = lst + e * NTOK;
    float inv_scale = 1.0f / (4.0f * fabsf(temp[0]));  // 1/(sqrt(HD)*|temp|)

    // stage K,V rows for this group into LDS (float4 granularity)
    for (int j = threadIdx.x; j < cs * 4; j += 256) {
        int i = j >> 2, comp = j & 3;
        int nk = (int)L[i];
        size_t rb = (size_t)(b * NTOK + nk) * DE + h * HD;
        ((float4*)Ksh[i])[comp] = ((const float4*)(K + rb))[comp];
        ((float4*)Vsh[i])[comp] = ((const float4*)(V + rb))[comp];
    }
    __syncthreads();

    for (int qi = tile + QT * threadIdx.x; qi < c; qi += QT * 256) {
        int nq = (int)L[qi];
        const float* qp = Q + ((size_t)(b * NTOK + nq) * DE + h * HD);
        float4 q0 = ((const float4*)qp)[0];
        float4 q1 = ((const float4*)qp)[1];
        float4 q2 = ((const float4*)qp)[2];
        float4 q3 = ((const float4*)qp)[3];

        // pass 1: max (LDS broadcast reads)
        float mx = -3.4e38f;
        for (int i = 0; i < cs; i++) {
            float4 k0 = ((const float4*)Ksh[i])[0];
            float4 k1 = ((const float4*)Ksh[i])[1];
            float4 k2 = ((const float4*)Ksh[i])[2];
            float4 k3 = ((const float4*)Ksh[i])[3];
            float d = q0.x*k0.x + q0.y*k0.y + q0.z*k0.z + q0.w*k0.w
                    + q1.x*k1.x + q1.y*k1.y + q1.z*k1.z + q1.w*k1.w
                    + q2.x*k2.x + q2.y*k2.y + q2.z*k2.z + q2.w*k2.w
                    + q3.x*k3.x + q3.y*k3.y + q3.z*k3.z + q3.w*k3.w;
            mx = fmaxf(mx, d * inv_scale);
        }
        for (int i = cs; i < c; i++) {   // safety tail (never taken at this data)
            int nk = (int)L[i];
            const float* kp = K + ((size_t)(b * NTOK + nk) * DE + h * HD);
            float d = 0.f;
            for (int dd = 0; dd < HD; dd++) d += qp[dd] * kp[dd];
            mx = fmaxf(mx, d * inv_scale);
        }

        // pass 2: sum + PV
        float l = 0.f;
        float4 a0 = {0,0,0,0}, a1 = {0,0,0,0}, a2 = {0,0,0,0}, a3 = {0,0,0,0};
        for (int i = 0; i < cs; i++) {
            float4 k0 = ((const float4*)Ksh[i])[0];
            float4 k1 = ((const float4*)Ksh[i])[1];
            float4 k2 = ((const float4*)Ksh[i])[2];
            float4 k3 = ((const float4*)Ksh[i])[3];
            float d = q0.x*k0.x + q0.y*k0.y + q0.z*k0.z + q0.w*k0.w
                    + q1.x*k1.x + q1.y*k1.y + q1.z*k1.z + q1.w*k1.w
                    + q2.x*k2.x + q2.y*k2.y + q2.z*k2.z + q2.w*k2.w
                    + q3.x*k3.x + q3.y*k3.y + q3.z*k3.z + q3.w*k3.w;
            float p = __expf(d * inv_scale - mx);
            l += p;
            float4 v0 = ((const float4*)Vsh[i])[0];
            float4 v1 = ((const float4*)Vsh[i])[1];
            float4 v2 = ((const float4*)Vsh[i])[2];
            float4 v3 = ((const float4*)Vsh[i])[3];
            a0.x += p*v0.x; a0.y += p*v0.y; a0.z += p*v0.z; a0.w += p*v0.w;
            a1.x += p*v1.x; a1.y += p*v1.y; a1.z += p*v1.z; a1.w += p*v1.w;
            a2.x += p*v2.x; a2.y += p*v2.y; a2.z += p*v2.z; a2.w += p*v2.w;
            a3.x += p*v3.x; a3.y += p*v3.y; a3.z += p*v3.z; a3.w += p*v3.w;
        }
        for (int i = cs; i < c; i++) {   // safety tail
            int nk = (int)L[i];
            size_t rb = (size_t)(b * NTOK + nk) * DE + h * HD;
            const float* kp = K + rb;
            float d = 0.f;
            for (int dd = 0; dd < HD; dd++) d += qp[dd] * kp[dd];
            float p = __expf(d * inv_scale - mx);
            l += p;
            const float* vp = V + rb;
            a0.x += p*vp[0];  a0.y += p*vp[1];  a0.z += p*vp[2];  a0.w += p*vp[3];
            a1.x += p*vp[4];  a1.y += p*vp[5];  a1.z += p*vp[6];  a1.w += p*vp[7];
            a2.x += p*vp[8];  a2.y += p*vp[9];  a2.z += p*vp[10]; a2.w += p*vp[11];
            a3.x += p*vp[12]; a3.y += p*vp[13]; a3.z += p*vp[14]; a3.w += p*vp[15];
        }
        float il = 1.0f / l;
        float* op = F + ((size_t)(b * NTOK + nq) * DE + h * HD);
        ((float4*)op)[0] = make_float4(a0.x*il, a0.y*il, a0.z*il, a0.w*il);
        ((float4*)op)[1] = make_float4(a1.x*il, a1.y*il, a1.z*il, a1.w*il);
        ((float4*)op)[2] = make_float4(a2.x*il, a2.y*il, a2.z*il, a2.w*il);
        ((float4*)op)[3] = make_float4(a3.x*il, a3.y*il, a3.z*il, a3.w*il);
    }
}

// ---------------- kernel 4: proj (coalesced WfT) + bias + residual, 8 tokens/block ----------------
__global__ __launch_bounds__(256) void k_proj(
    const float* __restrict__ x, const float* __restrict__ F,
    const float* __restrict__ WfT, const float* __restrict__ bf,
    float* __restrict__ out) {
    __shared__ float fr[8][DE];       // 4 KB
    int t0 = blockIdx.x * 8;
    int tid = threadIdx.x;
    ((float4*)fr)[tid] = ((const float4*)(F + (size_t)t0 * DE))[tid];
    __syncthreads();
    float acc0[8], acc1[8];
    float b0 = bf[tid], b1 = bf[tid + 256];
#pragma unroll
    for (int tk = 0; tk < 8; tk++) { acc0[tk] = b0; acc1[tk] = b1; }
#pragma unroll 4
    for (int k = 0; k < DE; k++) {
        float w0 = WfT[(size_t)k * DF + tid];
        float w1 = WfT[(size_t)k * DF + tid + 256];
#pragma unroll
        for (int tk = 0; tk < 8; tk++) {
            float fv = fr[tk][k];
            acc0[tk] += fv * w0;
            acc1[tk] += fv * w1;
        }
    }
#pragma unroll
    for (int tk = 0; tk < 8; tk++) {
        size_t rb = (size_t)(t0 + tk) * DF;
        out[rb + tid]       = x[rb + tid]       + acc0[tk];
        out[rb + tid + 256] = x[rb + tid + 256] + acc1[tk];
    }
}

extern "C" void kernel_launch(void* const* d_in, const int* in_sizes, int n_in,
                              void* d_out, int out_size, void* d_ws, size_t ws_size,
                              hipStream_t stream) {
    (void)in_sizes; (void)n_in; (void)out_size; (void)ws_size;
    const float* x     = (const float*)d_in[0];
    const float* fp    = (const float*)d_in[1];
    const float* lnw   = (const float*)d_in[2];
    const float* lnb   = (const float*)d_in[3];
    const float* alpha = (const float*)d_in[4];
    const float* Wg1   = (const float*)d_in[5];
    const float* bg1   = (const float*)d_in[6];
    const float* Wg2   = (const float*)d_in[7];
    const float* bg2   = (const float*)d_in[8];
    const float* Wq    = (const float*)d_in[9];
    const float* Wk    = (const float*)d_in[10];
    const float* Wv    = (const float*)d_in[11];
    const float* temp  = (const float*)d_in[12];
    const float* Wf    = (const float*)d_in[13];
    const float* bf    = (const float*)d_in[14];
    float* out = (float*)d_out;

    char* ws = (char*)d_ws;
    unsigned* cnt = (unsigned*)ws;                 // 32 B
    unsigned* lst = (unsigned*)(ws + 1024);        // 32 KB
    float* Q = (float*)(ws + 65536);               // 1 MB each
    float* K = Q + (size_t)B * NTOK * DE;
    float* V = K + (size_t)B * NTOK * DE;
    float* F = V + (size_t)B * NTOK * DE;
    float* WqT  = F + (size_t)B * NTOK * DE;       // 256 KB each
    float* WkT  = WqT + (size_t)E * S * DE;
    float* WvT  = WkT + (size_t)E * S * DE;
    float* Wg1T = WvT + (size_t)E * S * DE;        // 32 KB
    float* WfT  = Wg1T + (size_t)E * S * GH;       // 256 KB

    hipLaunchKernelGGL(k_transpose, dim3(72), dim3(256), 0, stream,
                       Wq, Wk, Wv, Wg1, Wf, WqT, WkT, WvT, Wg1T, WfT);
    hipLaunchKernelGGL(k_lists, dim3(E), dim3(64), 0, stream, fp, cnt, lst);
    hipLaunchKernelGGL(k_lnqkv, dim3(B * NTOK / 4), dim3(256), 0, stream,
                       x, fp, lnw, lnb, alpha, Wg1T, bg1, Wg2, bg2, WqT, WkT, WvT,
                       Q, K, V);
    hipLaunchKernelGGL(k_attn, dim3(B * E * H * QT), dim3(256), 0, stream,
                       Q, K, V, cnt, lst, temp, F);
    hipLaunchKernelGGL(k_proj, dim3(B * NTOK / 8), dim3(256), 0, stream,
                       x, F, WfT, bf, out);
}

// Round 4
// 60.511 us; speedup vs baseline: 3.5266x; 1.3296x over previous
//
#include <hip/hip_runtime.h>
#include <math.h>

#define E 8
#define DF 512
#define DE 128
#define H 8
#define S 64
#define GH 16
#define HD 16
#define B 2
#define NTOK 1024
#define QT 4          // query chunks per (b,e,h) group in k_attn
#define KMAX 256      // LDS-staged key capacity per group

__device__ __forceinline__ float wave_sum(float v) {
    for (int m = 32; m; m >>= 1) v += __shfl_xor(v, m, 64);
    return v;
}

// ---------------- kernel 0: weight transposes (reduction dim -> row dim) ----------------
// WqT/WkT/WvT: [E][S][DE], Wg1T: [E][S][GH], WfT: [DE][DF]
__global__ __launch_bounds__(256) void k_transpose(
    const float* __restrict__ Wq, const float* __restrict__ Wk,
    const float* __restrict__ Wv, const float* __restrict__ Wg1,
    const float* __restrict__ Wf,
    float* __restrict__ WqT, float* __restrict__ WkT, float* __restrict__ WvT,
    float* __restrict__ Wg1T, float* __restrict__ WfT) {
    __shared__ float sh[64][65];
    int bid = blockIdx.x;
    int tid = threadIdx.x;
    const float* in;
    float* out;
    int rows, istride, ostride;
    if (bid < 48) {                 // Wq/Wk/Wv: [128][64] per expert -> [64][128]
        int m = bid >> 4, e = (bid >> 1) & 7, dt = bid & 1;
        const float* W = (m == 0) ? Wq : (m == 1) ? Wk : Wv;
        float* WT      = (m == 0) ? WqT : (m == 1) ? WkT : WvT;
        in = W + (size_t)e * DE * S + (size_t)dt * 64 * S;
        out = WT + (size_t)e * S * DE + dt * 64;
        rows = 64; istride = S; ostride = DE;
    } else if (bid < 64) {          // Wf: [512][128] -> [128][512]
        int i = bid - 48, rt = i >> 1, ct = i & 1;
        in = Wf + (size_t)rt * 64 * DE + ct * 64;
        out = WfT + (size_t)ct * 64 * DF + rt * 64;
        rows = 64; istride = DE; ostride = DF;
    } else {                        // Wg1: [16][64] per expert -> [64][16]
        int e = bid - 64;
        in = Wg1 + (size_t)e * GH * S;
        out = Wg1T + (size_t)e * S * GH;
        rows = GH; istride = S; ostride = GH;
    }
    int c = tid & 63, r0 = tid >> 6;
    for (int r = r0; r < rows; r += 4) sh[r][c] = in[(size_t)r * istride + c];
    __syncthreads();
    if (c < rows) {
        for (int cc = r0; cc < 64; cc += 4)
            out[(size_t)cc * ostride + c] = sh[c][cc];
    }
}

// ---------------- kernel 1: deterministic expert token lists ----------------
__global__ void k_lists(const float* __restrict__ fp, unsigned* __restrict__ cnt,
                        unsigned* __restrict__ lst) {
    int e = blockIdx.x;
    int l = threadIdx.x;  // 64 threads = 1 wave
    unsigned c = 0;
    for (int base = 0; base < NTOK; base += 64) {
        int n = base + l;
        float f = fp[n];
        int ee = (int)(f * 8.0f);
        ee = ee > 7 ? 7 : ee;
        bool in = (ee == e);
        unsigned long long m = __ballot(in);
        unsigned pos = (unsigned)__popcll(m & ((1ull << l) - 1ull));
        if (in) lst[e * NTOK + c + pos] = (unsigned)n;
        c += (unsigned)__popcll(m);
    }
    if (l == 0) cnt[e] = c;
}

// ------------- kernel 2: LN + gate + QKV (own expert only), 1 wave/token -------------
__global__ __launch_bounds__(256) void k_lnqkv(
    const float* __restrict__ x, const float* __restrict__ fp,
    const float* __restrict__ lnw, const float* __restrict__ lnb,
    const float* __restrict__ alpha,
    const float* __restrict__ Wg1T, const float* __restrict__ bg1,
    const float* __restrict__ Wg2, const float* __restrict__ bg2,
    const float* __restrict__ WqT, const float* __restrict__ WkT,
    const float* __restrict__ WvT,
    float* __restrict__ Q, float* __restrict__ K, float* __restrict__ V) {
    __shared__ float fsh[4][64];
    int wave = threadIdx.x >> 6;
    int lane = threadIdx.x & 63;
    int t = blockIdx.x * 4 + wave;       // t = b*NTOK + n
    int n = t & (NTOK - 1);

    const float* xrow = x + (size_t)t * DF;
    float4 a  = *(const float4*)(xrow + lane * 8);
    float4 b4 = *(const float4*)(xrow + lane * 8 + 4);
    float s  = a.x + a.y + a.z + a.w + b4.x + b4.y + b4.z + b4.w;
    float ss = a.x*a.x + a.y*a.y + a.z*a.z + a.w*a.w
             + b4.x*b4.x + b4.y*b4.y + b4.z*b4.z + b4.w*b4.w;
    s = wave_sum(s);
    ss = wave_sum(ss);
    float mu  = s * (1.0f / DF);
    float var = ss * (1.0f / DF) - mu * mu;
    float rs  = rsqrtf(var + 1e-5f);

    int e = (int)(fp[n] * 8.0f);
    e = e > 7 ? 7 : e;

    float xv = xrow[e * 64 + lane];
    float f = (xv - mu) * rs * lnw[e * 64 + lane] + lnb[e * 64 + lane];
    fsh[wave][lane] = f;
    __syncthreads();

    // gate MLP: h = lane&15, s-range split across the 4 sixteen-lane groups
    int h = lane & 15;
    int sb = (lane >> 4) * 16;
    const float* wg1t = Wg1T + (size_t)e * S * GH;
    float g1p = 0.f;
#pragma unroll
    for (int si = 0; si < 16; si++)
        g1p += fsh[wave][sb + si] * wg1t[(size_t)(sb + si) * GH + h];
    g1p += __shfl_xor(g1p, 16, 64);
    g1p += __shfl_xor(g1p, 32, 64);
    float g1 = g1p + bg1[e * GH + h];
    g1 = 0.5f * g1 * (1.0f + erff(g1 * 0.70710678118654752f));  // exact gelu
    float part = g1 * Wg2[e * GH + h];
    part += __shfl_xor(part, 1, 64);
    part += __shfl_xor(part, 2, 64);
    part += __shfl_xor(part, 4, 64);
    part += __shfl_xor(part, 8, 64);
    float g2 = part + bg2[e];
    float gate = 1.0f / (1.0f + __expf(-g2));
    float aw = 1.0f / (1.0f + __expf(-alpha[e]));
    float gm = gate * aw + (1.0f - aw);
    f *= gm;
    __syncthreads();
    fsh[wave][lane] = f;
    __syncthreads();

    // QKV: lane owns dims d = lane*2, lane*2+1; coalesced float2 weight rows
    size_t wo = (size_t)e * S * DE;
    const float* Wqe = WqT + wo;
    const float* Wke = WkT + wo;
    const float* Wve = WvT + wo;
    float2 qa = {0.f, 0.f}, ka = {0.f, 0.f}, va = {0.f, 0.f};
    int d2 = lane * 2;
#pragma unroll 4
    for (int si = 0; si < S; si++) {
        float fv = fsh[wave][si];
        float2 wq = *(const float2*)(Wqe + (size_t)si * DE + d2);
        float2 wk = *(const float2*)(Wke + (size_t)si * DE + d2);
        float2 wv = *(const float2*)(Wve + (size_t)si * DE + d2);
        qa.x += fv * wq.x; qa.y += fv * wq.y;
        ka.x += fv * wk.x; ka.y += fv * wk.y;
        va.x += fv * wv.x; va.y += fv * wv.y;
    }
    size_t ob = (size_t)t * DE + d2;
    *(float2*)(Q + ob) = qa;
    *(float2*)(K + ob) = ka;
    *(float2*)(V + ob) = va;
}

// ------- kernel 3: block-diagonal attention, flash-split keys across 4 waves -------
// block = (b,e,h, query-chunk of 64). Each wave: 1/4 of keys, online softmax
// (defer-rescale THR=8), 1 query per lane. Merge partials via LDS.
__global__ __launch_bounds__(256) void k_attn(
    const float* __restrict__ Q, const float* __restrict__ K,
    const float* __restrict__ V, const unsigned* __restrict__ cnt,
    const unsigned* __restrict__ lst, const float* __restrict__ temp,
    float* __restrict__ F) {
    __shared__ float Ksh[KMAX][HD];       // 16 KB
    __shared__ float Vsh[KMAX][HD];       // 16 KB
    __shared__ float part[4][64][18];     // 18 KB: m, l, acc[16]
    int idx = blockIdx.x;                 // beh*QT + qt
    int qt = idx & (QT - 1);
    int beh = idx / QT;
    int b = beh >> 6;
    int e = (beh >> 3) & 7;
    int h = beh & 7;
    int c = (int)cnt[e];
    int qbase0 = qt * 64;
    if (qbase0 >= c) return;              // uniform per block
    int cs = c < KMAX ? c : KMAX;
    const unsigned* L = lst + e * NTOK;
    float inv_scale = 1.0f / (4.0f * fabsf(temp[0]));  // 1/(sqrt(HD)*|temp|)

    // stage K,V rows for this (b,e,h) into LDS
    for (int j = threadIdx.x; j < cs * 4; j += 256) {
        int i = j >> 2, comp = j & 3;
        int nk = (int)L[i];
        size_t rb = (size_t)(b * NTOK + nk) * DE + h * HD;
        ((float4*)Ksh[i])[comp] = ((const float4*)(K + rb))[comp];
        ((float4*)Vsh[i])[comp] = ((const float4*)(V + rb))[comp];
    }
    __syncthreads();

    int wave = threadIdx.x >> 6;
    int lane = threadIdx.x & 63;
    int ck = (c + 3) >> 2;                // keys per wave
    int k0 = wave * ck;
    int k1 = min(c, k0 + ck);

    for (int qb = qbase0; qb < c; qb += QT * 64) {   // 1 iter in practice
        int qi = qb + lane;
        bool valid = qi < c;
        int nq = (int)L[valid ? qi : c - 1];
        const float* qp = Q + ((size_t)(b * NTOK + nq) * DE + h * HD);
        float4 q0 = ((const float4*)qp)[0];
        float4 q1 = ((const float4*)qp)[1];
        float4 q2 = ((const float4*)qp)[2];
        float4 q3 = ((const float4*)qp)[3];
        q0.x *= inv_scale; q0.y *= inv_scale; q0.z *= inv_scale; q0.w *= inv_scale;
        q1.x *= inv_scale; q1.y *= inv_scale; q1.z *= inv_scale; q1.w *= inv_scale;
        q2.x *= inv_scale; q2.y *= inv_scale; q2.z *= inv_scale; q2.w *= inv_scale;
        q3.x *= inv_scale; q3.y *= inv_scale; q3.z *= inv_scale; q3.w *= inv_scale;

        float m = -INFINITY, l = 0.f;
        float4 a0 = {0,0,0,0}, a1 = {0,0,0,0}, a2 = {0,0,0,0}, a3 = {0,0,0,0};

        int kls = min(k1, cs);
        for (int i = k0; i < kls; i++) {
            float4 kk0 = ((const float4*)Ksh[i])[0];
            float4 kk1 = ((const float4*)Ksh[i])[1];
            float4 kk2 = ((const float4*)Ksh[i])[2];
            float4 kk3 = ((const float4*)Ksh[i])[3];
            float s = q0.x*kk0.x + q0.y*kk0.y + q0.z*kk0.z + q0.w*kk0.w
                    + q1.x*kk1.x + q1.y*kk1.y + q1.z*kk1.z + q1.w*kk1.w
                    + q2.x*kk2.x + q2.y*kk2.y + q2.z*kk2.z + q2.w*kk2.w
                    + q3.x*kk3.x + q3.y*kk3.y + q3.z*kk3.z + q3.w*kk3.w;
            if (__any(s - m > 8.0f)) {            // rare after warm-up
                float mn = fmaxf(m, s);
                float r = __expf(m - mn);
                l *= r;
                a0.x*=r; a0.y*=r; a0.z*=r; a0.w*=r;
                a1.x*=r; a1.y*=r; a1.z*=r; a1.w*=r;
                a2.x*=r; a2.y*=r; a2.z*=r; a2.w*=r;
                a3.x*=r; a3.y*=r; a3.z*=r; a3.w*=r;
                m = mn;
            }
            float p = __expf(s - m);
            l += p;
            float4 v0 = ((const float4*)Vsh[i])[0];
            float4 v1 = ((const float4*)Vsh[i])[1];
            float4 v2 = ((const float4*)Vsh[i])[2];
            float4 v3 = ((const float4*)Vsh[i])[3];
            a0.x += p*v0.x; a0.y += p*v0.y; a0.z += p*v0.z; a0.w += p*v0.w;
            a1.x += p*v1.x; a1.y += p*v1.y; a1.z += p*v1.z; a1.w += p*v1.w;
            a2.x += p*v2.x; a2.y += p*v2.y; a2.z += p*v2.z; a2.w += p*v2.w;
            a3.x += p*v3.x; a3.y += p*v3.y; a3.z += p*v3.z; a3.w += p*v3.w;
        }
        for (int i = max(k0, cs); i < k1; i++) {   // global fallback (never taken here)
            int nk = (int)L[i];
            size_t rb = (size_t)(b * NTOK + nk) * DE + h * HD;
            const float* kp = K + rb;
            float s = 0.f;
            s += q0.x*kp[0] + q0.y*kp[1] + q0.z*kp[2] + q0.w*kp[3];
            s += q1.x*kp[4] + q1.y*kp[5] + q1.z*kp[6] + q1.w*kp[7];
            s += q2.x*kp[8] + q2.y*kp[9] + q2.z*kp[10] + q2.w*kp[11];
            s += q3.x*kp[12] + q3.y*kp[13] + q3.z*kp[14] + q3.w*kp[15];
            if (__any(s - m > 8.0f)) {
                float mn = fmaxf(m, s);
                float r = __expf(m - mn);
                l *= r;
                a0.x*=r; a0.y*=r; a0.z*=r; a0.w*=r;
                a1.x*=r; a1.y*=r; a1.z*=r; a1.w*=r;
                a2.x*=r; a2.y*=r; a2.z*=r; a2.w*=r;
                a3.x*=r; a3.y*=r; a3.z*=r; a3.w*=r;
                m = mn;
            }
            float p = __expf(s - m);
            l += p;
            const float* vp = V + rb;
            a0.x += p*vp[0];  a0.y += p*vp[1];  a0.z += p*vp[2];  a0.w += p*vp[3];
            a1.x += p*vp[4];  a1.y += p*vp[5];  a1.z += p*vp[6];  a1.w += p*vp[7];
            a2.x += p*vp[8];  a2.y += p*vp[9];  a2.z += p*vp[10]; a2.w += p*vp[11];
            a3.x += p*vp[12]; a3.y += p*vp[13]; a3.z += p*vp[14]; a3.w += p*vp[15];
        }

        // publish partials
        float* pp = part[wave][lane];
        pp[0] = m; pp[1] = l;
        pp[2]  = a0.x; pp[3]  = a0.y; pp[4]  = a0.z; pp[5]  = a0.w;
        pp[6]  = a1.x; pp[7]  = a1.y; pp[8]  = a1.z; pp[9]  = a1.w;
        pp[10] = a2.x; pp[11] = a2.y; pp[12] = a2.z; pp[13] = a2.w;
        pp[14] = a3.x; pp[15] = a3.y; pp[16] = a3.z; pp[17] = a3.w;
        __syncthreads();

        if (wave == 0) {
            float M = part[0][lane][0];
            M = fmaxf(M, part[1][lane][0]);
            M = fmaxf(M, part[2][lane][0]);
            M = fmaxf(M, part[3][lane][0]);
            float Lt = 0.f;
            float o[16];
#pragma unroll
            for (int j = 0; j < 16; j++) o[j] = 0.f;
#pragma unroll
            for (int w = 0; w < 4; w++) {
                const float* qq = part[w][lane];
                float r = __expf(qq[0] - M);
                Lt += qq[1] * r;
#pragma unroll
                for (int j = 0; j < 16; j++) o[j] += qq[2 + j] * r;
            }
            if (valid) {
                float il = 1.0f / Lt;
                float* op = F + ((size_t)(b * NTOK + nq) * DE + h * HD);
#pragma unroll
                for (int j = 0; j < 4; j++)
                    ((float4*)op)[j] = make_float4(o[4*j]*il, o[4*j+1]*il,
                                                   o[4*j+2]*il, o[4*j+3]*il);
            }
        }
        __syncthreads();   // protect `part` reuse if another query chunk follows
    }
}

// ---------------- kernel 4: proj (coalesced WfT) + bias + residual, 8 tokens/block ----------------
__global__ __launch_bounds__(256) void k_proj(
    const float* __restrict__ x, const float* __restrict__ F,
    const float* __restrict__ WfT, const float* __restrict__ bf,
    float* __restrict__ out) {
    __shared__ float fr[8][DE];       // 4 KB
    int t0 = blockIdx.x * 8;
    int tid = threadIdx.x;
    ((float4*)fr)[tid] = ((const float4*)(F + (size_t)t0 * DE))[tid];
    __syncthreads();
    float acc0[8], acc1[8];
    float b0 = bf[tid], b1 = bf[tid + 256];
#pragma unroll
    for (int tk = 0; tk < 8; tk++) { acc0[tk] = b0; acc1[tk] = b1; }
#pragma unroll 4
    for (int k = 0; k < DE; k++) {
        float w0 = WfT[(size_t)k * DF + tid];
        float w1 = WfT[(size_t)k * DF + tid + 256];
#pragma unroll
        for (int tk = 0; tk < 8; tk++) {
            float fv = fr[tk][k];
            acc0[tk] += fv * w0;
            acc1[tk] += fv * w1;
        }
    }
#pragma unroll
    for (int tk = 0; tk < 8; tk++) {
        size_t rb = (size_t)(t0 + tk) * DF;
        out[rb + tid]       = x[rb + tid]       + acc0[tk];
        out[rb + tid + 256] = x[rb + tid + 256] + acc1[tk];
    }
}

extern "C" void kernel_launch(void* const* d_in, const int* in_sizes, int n_in,
                              void* d_out, int out_size, void* d_ws, size_t ws_size,
                              hipStream_t stream) {
    (void)in_sizes; (void)n_in; (void)out_size; (void)ws_size;
    const float* x     = (const float*)d_in[0];
    const float* fp    = (const float*)d_in[1];
    const float* lnw   = (const float*)d_in[2];
    const float* lnb   = (const float*)d_in[3];
    const float* alpha = (const float*)d_in[4];
    const float* Wg1   = (const float*)d_in[5];
    const float* bg1   = (const float*)d_in[6];
    const float* Wg2   = (const float*)d_in[7];
    const float* bg2   = (const float*)d_in[8];
    const float* Wq    = (const float*)d_in[9];
    const float* Wk    = (const float*)d_in[10];
    const float* Wv    = (const float*)d_in[11];
    const float* temp  = (const float*)d_in[12];
    const float* Wf    = (const float*)d_in[13];
    const float* bf    = (const float*)d_in[14];
    float* out = (float*)d_out;

    char* ws = (char*)d_ws;
    unsigned* cnt = (unsigned*)ws;                 // 32 B
    unsigned* lst = (unsigned*)(ws + 1024);        // 32 KB
    float* Q = (float*)(ws + 65536);               // 1 MB each
    float* K = Q + (size_t)B * NTOK * DE;
    float* V = K + (size_t)B * NTOK * DE;
    float* F = V + (size_t)B * NTOK * DE;
    float* WqT  = F + (size_t)B * NTOK * DE;       // 256 KB each
    float* WkT  = WqT + (size_t)E * S * DE;
    float* WvT  = WkT + (size_t)E * S * DE;
    float* Wg1T = WvT + (size_t)E * S * DE;        // 32 KB
    float* WfT  = Wg1T + (size_t)E * S * GH;       // 256 KB

    hipLaunchKernelGGL(k_transpose, dim3(72), dim3(256), 0, stream,
                       Wq, Wk, Wv, Wg1, Wf, WqT, WkT, WvT, Wg1T, WfT);
    hipLaunchKernelGGL(k_lists, dim3(E), dim3(64), 0, stream, fp, cnt, lst);
    hipLaunchKernelGGL(k_lnqkv, dim3(B * NTOK / 4), dim3(256), 0, stream,
                       x, fp, lnw, lnb, alpha, Wg1T, bg1, Wg2, bg2, WqT, WkT, WvT,
                       Q, K, V);
    hipLaunchKernelGGL(k_attn, dim3(B * E * H * QT), dim3(256), 0, stream,
                       Q, K, V, cnt, lst, temp, F);
    hipLaunchKernelGGL(k_proj, dim3(B * NTOK / 8), dim3(256), 0, stream,
                       x, F, WfT, bf, out);
}

// Round 5
// 53.753 us; speedup vs baseline: 3.9699x; 1.1257x over previous
//
#include <hip/hip_runtime.h>
#include <math.h>

#define E 8
#define DF 512
#define DE 128
#define H 8
#define S 64
#define GH 16
#define HD 16
#define B 2
#define NTOK 1024
#define QT 4          // query chunks per (b,e,h) group in k_attn
#define KMAX 256      // LDS-staged key capacity per group

__device__ __forceinline__ float wave_sum(float v) {
    for (int m = 32; m; m >>= 1) v += __shfl_xor(v, m, 64);
    return v;
}

// -------- kernel 0: prep = weight transposes (blocks 0..71) + expert lists (72..79) --------
// WqT/WkT/WvT: [E][S][DE], Wg1T: [E][S][GH], WfT: [DE][DF]
__global__ __launch_bounds__(256) void k_prep(
    const float* __restrict__ Wq, const float* __restrict__ Wk,
    const float* __restrict__ Wv, const float* __restrict__ Wg1,
    const float* __restrict__ Wf, const float* __restrict__ fp,
    float* __restrict__ WqT, float* __restrict__ WkT, float* __restrict__ WvT,
    float* __restrict__ Wg1T, float* __restrict__ WfT,
    unsigned* __restrict__ cnt, unsigned* __restrict__ lst) {
    __shared__ float sh[64][65];
    int bid = blockIdx.x;
    int tid = threadIdx.x;
    if (bid >= 72) {                // ---- expert token lists (1 wave) ----
        if (tid >= 64) return;
        int e = bid - 72;
        int l = tid;
        unsigned c = 0;
        for (int base = 0; base < NTOK; base += 64) {
            int n = base + l;
            float f = fp[n];
            int ee = (int)(f * 8.0f);
            ee = ee > 7 ? 7 : ee;
            bool in = (ee == e);
            unsigned long long m = __ballot(in);
            unsigned pos = (unsigned)__popcll(m & ((1ull << l) - 1ull));
            if (in) lst[e * NTOK + c + pos] = (unsigned)n;
            c += (unsigned)__popcll(m);
        }
        if (l == 0) cnt[e] = c;
        return;
    }
    const float* in;
    float* out;
    int rows, istride, ostride;
    if (bid < 48) {                 // Wq/Wk/Wv: [128][64] per expert -> [64][128]
        int m = bid >> 4, e = (bid >> 1) & 7, dt = bid & 1;
        const float* W = (m == 0) ? Wq : (m == 1) ? Wk : Wv;
        float* WT      = (m == 0) ? WqT : (m == 1) ? WkT : WvT;
        in = W + (size_t)e * DE * S + (size_t)dt * 64 * S;
        out = WT + (size_t)e * S * DE + dt * 64;
        rows = 64; istride = S; ostride = DE;
    } else if (bid < 64) {          // Wf: [512][128] -> [128][512]
        int i = bid - 48, rt = i >> 1, ct = i & 1;
        in = Wf + (size_t)rt * 64 * DE + ct * 64;
        out = WfT + (size_t)ct * 64 * DF + rt * 64;
        rows = 64; istride = DE; ostride = DF;
    } else {                        // Wg1: [16][64] per expert -> [64][16]
        int e = bid - 64;
        in = Wg1 + (size_t)e * GH * S;
        out = Wg1T + (size_t)e * S * GH;
        rows = GH; istride = S; ostride = GH;
    }
    int c = tid & 63, r0 = tid >> 6;
    for (int r = r0; r < rows; r += 4) sh[r][c] = in[(size_t)r * istride + c];
    __syncthreads();
    if (c < rows) {
        for (int cc = r0; cc < 64; cc += 4)
            out[(size_t)cc * ostride + c] = sh[c][cc];
    }
}

// ------- kernel 2: LN + gate + QKV, expert-grouped, 4 tokens/wave weight reuse -------
// block = (b, e, chunk of 16 list slots); wave = 4 tokens; lane owns dims d=2*lane,2*lane+1
__global__ __launch_bounds__(256) void k_lnqkv(
    const float* __restrict__ x,
    const float* __restrict__ lnw, const float* __restrict__ lnb,
    const float* __restrict__ alpha,
    const float* __restrict__ Wg1T, const float* __restrict__ bg1,
    const float* __restrict__ Wg2, const float* __restrict__ bg2,
    const float* __restrict__ WqT, const float* __restrict__ WkT,
    const float* __restrict__ WvT,
    const unsigned* __restrict__ cnt, const unsigned* __restrict__ lst,
    float* __restrict__ Q, float* __restrict__ K, float* __restrict__ V) {
    __shared__ float fsh[4][4][68];      // padded: banks differ per token row
    int wave = threadIdx.x >> 6;
    int lane = threadIdx.x & 63;
    int bid = blockIdx.x;                // b*128 + e*16 + chunk
    int chunk = bid & 15;
    int e = (bid >> 4) & 7;
    int b = bid >> 7;
    int c = (int)cnt[e];
    if (chunk * 16 >= c) return;         // uniform per block
    const unsigned* L = lst + e * NTOK;
    float aw = 1.0f / (1.0f + __expf(-alpha[e]));
    size_t wo = (size_t)e * S * DE;
    const float* Wqe = WqT + wo;
    const float* Wke = WkT + wo;
    const float* Wve = WvT + wo;
    const float* wg1 = Wg1T + (size_t)e * S * GH + (lane & 15);
    float lw = lnw[e * 64 + lane], lb = lnb[e * 64 + lane];

    for (int it = 0; chunk * 16 + it * 256 < c; ++it) {    // block-uniform trip count
        int ib = it * 256 + chunk * 16 + wave * 4;         // first list slot of this wave
        int nj[4];
        // phase 1: LN stats + f slice for 4 tokens
        for (int j = 0; j < 4; j++) {
            int ti = ib + j;
            int n = (int)L[ti < c ? ti : c - 1];
            nj[j] = n;
            const float* xr = x + (size_t)(b * NTOK + n) * DF;
            float4 a  = *(const float4*)(xr + lane * 8);
            float4 b4 = *(const float4*)(xr + lane * 8 + 4);
            float s  = a.x + a.y + a.z + a.w + b4.x + b4.y + b4.z + b4.w;
            float ss = a.x*a.x + a.y*a.y + a.z*a.z + a.w*a.w
                     + b4.x*b4.x + b4.y*b4.y + b4.z*b4.z + b4.w*b4.w;
            s = wave_sum(s);
            ss = wave_sum(ss);
            float mu  = s * (1.0f / DF);
            float var = ss * (1.0f / DF) - mu * mu;
            float rs  = rsqrtf(var + 1e-5f);
            float f = (xr[e * 64 + lane] - mu) * rs * lw + lb;
            fsh[wave][j][lane] = f;
        }
        __syncthreads();
        // phase 2: gate MLP, 4 tokens in parallel (lane = tok*16 + h)
        {
            int j = lane >> 4, h = lane & 15;
            float g1 = bg1[e * GH + h];
#pragma unroll 8
            for (int si = 0; si < 64; si++)
                g1 += fsh[wave][j][si] * wg1[(size_t)si * GH];
            g1 = 0.5f * g1 * (1.0f + erff(g1 * 0.70710678118654752f));
            float part = g1 * Wg2[e * GH + h];
            part += __shfl_xor(part, 1, 64);
            part += __shfl_xor(part, 2, 64);
            part += __shfl_xor(part, 4, 64);
            part += __shfl_xor(part, 8, 64);
            float g2 = part + bg2[e];
            float gate = 1.0f / (1.0f + __expf(-g2));
            float gm = gate * aw + (1.0f - aw);
#pragma unroll
            for (int k = 0; k < 4; k++) fsh[wave][j][h * 4 + k] *= gm;
        }
        __syncthreads();
        // phase 3: QKV, one weight stream feeds 4 tokens
        int d2 = lane * 2;
        float2 qa[4], ka[4], va[4];
#pragma unroll
        for (int j = 0; j < 4; j++) { qa[j] = {0,0}; ka[j] = {0,0}; va[j] = {0,0}; }
#pragma unroll 4
        for (int si = 0; si < S; si++) {
            float2 wq = *(const float2*)(Wqe + (size_t)si * DE + d2);
            float2 wk = *(const float2*)(Wke + (size_t)si * DE + d2);
            float2 wv = *(const float2*)(Wve + (size_t)si * DE + d2);
#pragma unroll
            for (int j = 0; j < 4; j++) {
                float fv = fsh[wave][j][si];
                qa[j].x += fv * wq.x; qa[j].y += fv * wq.y;
                ka[j].x += fv * wk.x; ka[j].y += fv * wk.y;
                va[j].x += fv * wv.x; va[j].y += fv * wv.y;
            }
        }
#pragma unroll
        for (int j = 0; j < 4; j++) {
            if (ib + j < c) {
                size_t ob = (size_t)(b * NTOK + nj[j]) * DE + d2;
                *(float2*)(Q + ob) = qa[j];
                *(float2*)(K + ob) = ka[j];
                *(float2*)(V + ob) = va[j];
            }
        }
        __syncthreads();   // fsh reused next iteration
    }
}

// ------- kernel 3: block-diagonal attention, flash-split keys across 4 waves -------
__global__ __launch_bounds__(256) void k_attn(
    const float* __restrict__ Q, const float* __restrict__ K,
    const float* __restrict__ V, const unsigned* __restrict__ cnt,
    const unsigned* __restrict__ lst, const float* __restrict__ temp,
    float* __restrict__ F) {
    __shared__ float Ksh[KMAX][HD];       // 16 KB
    __shared__ float Vsh[KMAX][HD];       // 16 KB
    __shared__ float part[4][64][18];     // 18 KB: m, l, acc[16]
    int idx = blockIdx.x;                 // beh*QT + qt
    int qt = idx & (QT - 1);
    int beh = idx / QT;
    int b = beh >> 6;
    int e = (beh >> 3) & 7;
    int h = beh & 7;
    int c = (int)cnt[e];
    int qbase0 = qt * 64;
    if (qbase0 >= c) return;              // uniform per block
    int cs = c < KMAX ? c : KMAX;
    const unsigned* L = lst + e * NTOK;
    float inv_scale = 1.0f / (4.0f * fabsf(temp[0]));  // 1/(sqrt(HD)*|temp|)

    for (int j = threadIdx.x; j < cs * 4; j += 256) {
        int i = j >> 2, comp = j & 3;
        int nk = (int)L[i];
        size_t rb = (size_t)(b * NTOK + nk) * DE + h * HD;
        ((float4*)Ksh[i])[comp] = ((const float4*)(K + rb))[comp];
        ((float4*)Vsh[i])[comp] = ((const float4*)(V + rb))[comp];
    }
    __syncthreads();

    int wave = threadIdx.x >> 6;
    int lane = threadIdx.x & 63;
    int ck = (c + 3) >> 2;
    int k0 = wave * ck;
    int k1 = min(c, k0 + ck);

    for (int qb = qbase0; qb < c; qb += QT * 64) {
        int qi = qb + lane;
        bool valid = qi < c;
        int nq = (int)L[valid ? qi : c - 1];
        const float* qp = Q + ((size_t)(b * NTOK + nq) * DE + h * HD);
        float4 q0 = ((const float4*)qp)[0];
        float4 q1 = ((const float4*)qp)[1];
        float4 q2 = ((const float4*)qp)[2];
        float4 q3 = ((const float4*)qp)[3];
        q0.x *= inv_scale; q0.y *= inv_scale; q0.z *= inv_scale; q0.w *= inv_scale;
        q1.x *= inv_scale; q1.y *= inv_scale; q1.z *= inv_scale; q1.w *= inv_scale;
        q2.x *= inv_scale; q2.y *= inv_scale; q2.z *= inv_scale; q2.w *= inv_scale;
        q3.x *= inv_scale; q3.y *= inv_scale; q3.z *= inv_scale; q3.w *= inv_scale;

        float m = -INFINITY, l = 0.f;
        float4 a0 = {0,0,0,0}, a1 = {0,0,0,0}, a2 = {0,0,0,0}, a3 = {0,0,0,0};

        int kls = min(k1, cs);
        for (int i = k0; i < kls; i++) {
            float4 kk0 = ((const float4*)Ksh[i])[0];
            float4 kk1 = ((const float4*)Ksh[i])[1];
            float4 kk2 = ((const float4*)Ksh[i])[2];
            float4 kk3 = ((const float4*)Ksh[i])[3];
            float s = q0.x*kk0.x + q0.y*kk0.y + q0.z*kk0.z + q0.w*kk0.w
                    + q1.x*kk1.x + q1.y*kk1.y + q1.z*kk1.z + q1.w*kk1.w
                    + q2.x*kk2.x + q2.y*kk2.y + q2.z*kk2.z + q2.w*kk2.w
                    + q3.x*kk3.x + q3.y*kk3.y + q3.z*kk3.z + q3.w*kk3.w;
            if (__any(s - m > 8.0f)) {
                float mn = fmaxf(m, s);
                float r = __expf(m - mn);
                l *= r;
                a0.x*=r; a0.y*=r; a0.z*=r; a0.w*=r;
                a1.x*=r; a1.y*=r; a1.z*=r; a1.w*=r;
                a2.x*=r; a2.y*=r; a2.z*=r; a2.w*=r;
                a3.x*=r; a3.y*=r; a3.z*=r; a3.w*=r;
                m = mn;
            }
            float p = __expf(s - m);
            l += p;
            float4 v0 = ((const float4*)Vsh[i])[0];
            float4 v1 = ((const float4*)Vsh[i])[1];
            float4 v2 = ((const float4*)Vsh[i])[2];
            float4 v3 = ((const float4*)Vsh[i])[3];
            a0.x += p*v0.x; a0.y += p*v0.y; a0.z += p*v0.z; a0.w += p*v0.w;
            a1.x += p*v1.x; a1.y += p*v1.y; a1.z += p*v1.z; a1.w += p*v1.w;
            a2.x += p*v2.x; a2.y += p*v2.y; a2.z += p*v2.z; a2.w += p*v2.w;
            a3.x += p*v3.x; a3.y += p*v3.y; a3.z += p*v3.z; a3.w += p*v3.w;
        }
        for (int i = max(k0, cs); i < k1; i++) {   // global fallback (never taken here)
            int nk = (int)L[i];
            size_t rb = (size_t)(b * NTOK + nk) * DE + h * HD;
            const float* kp = K + rb;
            float s = 0.f;
            s += q0.x*kp[0] + q0.y*kp[1] + q0.z*kp[2] + q0.w*kp[3];
            s += q1.x*kp[4] + q1.y*kp[5] + q1.z*kp[6] + q1.w*kp[7];
            s += q2.x*kp[8] + q2.y*kp[9] + q2.z*kp[10] + q2.w*kp[11];
            s += q3.x*kp[12] + q3.y*kp[13] + q3.z*kp[14] + q3.w*kp[15];
            if (__any(s - m > 8.0f)) {
                float mn = fmaxf(m, s);
                float r = __expf(m - mn);
                l *= r;
                a0.x*=r; a0.y*=r; a0.z*=r; a0.w*=r;
                a1.x*=r; a1.y*=r; a1.z*=r; a1.w*=r;
                a2.x*=r; a2.y*=r; a2.z*=r; a2.w*=r;
                a3.x*=r; a3.y*=r; a3.z*=r; a3.w*=r;
                m = mn;
            }
            float p = __expf(s - m);
            l += p;
            const float* vp = V + rb;
            a0.x += p*vp[0];  a0.y += p*vp[1];  a0.z += p*vp[2];  a0.w += p*vp[3];
            a1.x += p*vp[4];  a1.y += p*vp[5];  a1.z += p*vp[6];  a1.w += p*vp[7];
            a2.x += p*vp[8];  a2.y += p*vp[9];  a2.z += p*vp[10]; a2.w += p*vp[11];
            a3.x += p*vp[12]; a3.y += p*vp[13]; a3.z += p*vp[14]; a3.w += p*vp[15];
        }

        float* pp = part[wave][lane];
        pp[0] = m; pp[1] = l;
        pp[2]  = a0.x; pp[3]  = a0.y; pp[4]  = a0.z; pp[5]  = a0.w;
        pp[6]  = a1.x; pp[7]  = a1.y; pp[8]  = a1.z; pp[9]  = a1.w;
        pp[10] = a2.x; pp[11] = a2.y; pp[12] = a2.z; pp[13] = a2.w;
        pp[14] = a3.x; pp[15] = a3.y; pp[16] = a3.z; pp[17] = a3.w;
        __syncthreads();

        if (wave == 0) {
            float M = part[0][lane][0];
            M = fmaxf(M, part[1][lane][0]);
            M = fmaxf(M, part[2][lane][0]);
            M = fmaxf(M, part[3][lane][0]);
            float Lt = 0.f;
            float o[16];
#pragma unroll
            for (int j = 0; j < 16; j++) o[j] = 0.f;
#pragma unroll
            for (int w = 0; w < 4; w++) {
                const float* qq = part[w][lane];
                float r = __expf(qq[0] - M);
                Lt += qq[1] * r;
#pragma unroll
                for (int j = 0; j < 16; j++) o[j] += qq[2 + j] * r;
            }
            if (valid) {
                float il = 1.0f / Lt;
                float* op = F + ((size_t)(b * NTOK + nq) * DE + h * HD);
#pragma unroll
                for (int j = 0; j < 4; j++)
                    ((float4*)op)[j] = make_float4(o[4*j]*il, o[4*j+1]*il,
                                                   o[4*j+2]*il, o[4*j+3]*il);
            }
        }
        __syncthreads();
    }
}

// ---------------- kernel 4: proj (coalesced WfT) + bias + residual, 8 tokens/block ----------------
__global__ __launch_bounds__(256) void k_proj(
    const float* __restrict__ x, const float* __restrict__ F,
    const float* __restrict__ WfT, const float* __restrict__ bf,
    float* __restrict__ out) {
    __shared__ float fr[8][DE];       // 4 KB
    int t0 = blockIdx.x * 8;
    int tid = threadIdx.x;
    ((float4*)fr)[tid] = ((const float4*)(F + (size_t)t0 * DE))[tid];
    __syncthreads();
    float acc0[8], acc1[8];
    float b0 = bf[tid], b1 = bf[tid + 256];
#pragma unroll
    for (int tk = 0; tk < 8; tk++) { acc0[tk] = b0; acc1[tk] = b1; }
#pragma unroll 4
    for (int k = 0; k < DE; k++) {
        float w0 = WfT[(size_t)k * DF + tid];
        float w1 = WfT[(size_t)k * DF + tid + 256];
#pragma unroll
        for (int tk = 0; tk < 8; tk++) {
            float fv = fr[tk][k];
            acc0[tk] += fv * w0;
            acc1[tk] += fv * w1;
        }
    }
#pragma unroll
    for (int tk = 0; tk < 8; tk++) {
        size_t rb = (size_t)(t0 + tk) * DF;
        out[rb + tid]       = x[rb + tid]       + acc0[tk];
        out[rb + tid + 256] = x[rb + tid + 256] + acc1[tk];
    }
}

extern "C" void kernel_launch(void* const* d_in, const int* in_sizes, int n_in,
                              void* d_out, int out_size, void* d_ws, size_t ws_size,
                              hipStream_t stream) {
    (void)in_sizes; (void)n_in; (void)out_size; (void)ws_size;
    const float* x     = (const float*)d_in[0];
    const float* fp    = (const float*)d_in[1];
    const float* lnw   = (const float*)d_in[2];
    const float* lnb   = (const float*)d_in[3];
    const float* alpha = (const float*)d_in[4];
    const float* Wg1   = (const float*)d_in[5];
    const float* bg1   = (const float*)d_in[6];
    const float* Wg2   = (const float*)d_in[7];
    const float* bg2   = (const float*)d_in[8];
    const float* Wq    = (const float*)d_in[9];
    const float* Wk    = (const float*)d_in[10];
    const float* Wv    = (const float*)d_in[11];
    const float* temp  = (const float*)d_in[12];
    const float* Wf    = (const float*)d_in[13];
    const float* bf    = (const float*)d_in[14];
    float* out = (float*)d_out;

    char* ws = (char*)d_ws;
    unsigned* cnt = (unsigned*)ws;                 // 32 B
    unsigned* lst = (unsigned*)(ws + 1024);        // 32 KB
    float* Q = (float*)(ws + 65536);               // 1 MB each
    float* K = Q + (size_t)B * NTOK * DE;
    float* V = K + (size_t)B * NTOK * DE;
    float* F = V + (size_t)B * NTOK * DE;
    float* WqT  = F + (size_t)B * NTOK * DE;       // 256 KB each
    float* WkT  = WqT + (size_t)E * S * DE;
    float* WvT  = WkT + (size_t)E * S * DE;
    float* Wg1T = WvT + (size_t)E * S * DE;        // 32 KB
    float* WfT  = Wg1T + (size_t)E * S * GH;       // 256 KB

    hipLaunchKernelGGL(k_prep, dim3(80), dim3(256), 0, stream,
                       Wq, Wk, Wv, Wg1, Wf, fp, WqT, WkT, WvT, Wg1T, WfT, cnt, lst);
    hipLaunchKernelGGL(k_lnqkv, dim3(B * E * 16), dim3(256), 0, stream,
                       x, lnw, lnb, alpha, Wg1T, bg1, Wg2, bg2, WqT, WkT, WvT,
                       cnt, lst, Q, K, V);
    hipLaunchKernelGGL(k_attn, dim3(B * E * H * QT), dim3(256), 0, stream,
                       Q, K, V, cnt, lst, temp, F);
    hipLaunchKernelGGL(k_proj, dim3(B * NTOK / 8), dim3(256), 0, stream,
                       x, F, WfT, bf, out);
}